// Round 1
// baseline (3105.100 us; speedup 1.0000x reference)
//
#include <hip/hip_runtime.h>

// Problem constants (B=8, S=4096, D=64, ds=16)
#define BATCH   8
#define SEQ     4096
#define DM      64
#define DS      16
#define BS      (BATCH*SEQ)      // 32768 timesteps
#define CHUNK   64               // scan chunk length
#define NCH     (SEQ/CHUNK)      // 64 chunks per batch
#define NCH_TOT (BATCH*NCH)      // 512 chunks total

// ---------------------------------------------------------------------------
// helper: 64-dot of an LDS x-row (broadcast float4 reads) with a register col
// ---------------------------------------------------------------------------
__device__ __forceinline__ float dot64(const float* xrow, const float col[64], float init) {
  float a0 = init, a1 = 0.f, a2 = 0.f, a3 = 0.f;
  #pragma unroll
  for (int e4 = 0; e4 < 16; ++e4) {
    float4 xv = *(const float4*)(xrow + e4 * 4);
    a0 += xv.x * col[e4 * 4 + 0];
    a1 += xv.y * col[e4 * 4 + 1];
    a2 += xv.z * col[e4 * 4 + 2];
    a3 += xv.w * col[e4 * 4 + 3];
  }
  return (a0 + a1) + (a2 + a3);
}

// ---------------------------------------------------------------------------
// K1: per-timestep selective params.  A_t (16x16) and Bx_t (16) for 64
// timesteps per block.  256 threads.
// ---------------------------------------------------------------------------
__global__ __launch_bounds__(256) void k1_params(
    const float* __restrict__ x,
    const float* __restrict__ WA, const float* __restrict__ bA,
    const float* __restrict__ WB, const float* __restrict__ bB,
    float* __restrict__ A_ws, float* __restrict__ Bx_ws)
{
  __shared__ __align__(16) float xs[64][64];
  const int tid = threadIdx.x;
  const int t0  = blockIdx.x * 64;

  { // stage x tile (64x64 fp32 = 16KB), coalesced float4
    const float4* xg = (const float4*)(x + (size_t)t0 * DM);
    float4* xsv = (float4*)&xs[0][0];
    #pragma unroll
    for (int i = 0; i < 4; ++i) xsv[tid + 256 * i] = xg[tid + 256 * i];
  }
  __syncthreads();

  // ---- A: thread j owns W_A column j (coalesced, L2-hot) ----
  {
    float col[64];
    #pragma unroll
    for (int e = 0; e < 64; ++e) col[e] = WA[e * 256 + tid];
    const float bias = bA[tid];
    for (int t = 0; t < 64; ++t) {
      A_ws[(size_t)(t0 + t) * 256 + tid] = dot64(&xs[t][0], col, bias);
    }
  }

  // ---- Bx: quadratic form, wave w handles n = p*4 + w, lane = d ----
  const int lane = tid & 63;
  const int wave = tid >> 6;
  for (int p = 0; p < 4; ++p) {
    const int n = p * 4 + wave;
    float col[64];
    #pragma unroll
    for (int e = 0; e < 64; ++e) col[e] = WB[e * 1024 + n * 64 + lane];
    const float bias = bB[n * 64 + lane];
    for (int t = 0; t < 64; ++t) {
      float contrib = dot64(&xs[t][0], col, bias) * xs[t][lane];
      #pragma unroll
      for (int off = 32; off; off >>= 1)
        contrib += __shfl_xor(contrib, off, 64);
      if (lane == 0) Bx_ws[(size_t)(t0 + t) * DS + n] = contrib;
    }
  }
}

// ---------------------------------------------------------------------------
// K2: per-chunk cumulative transition:  P_c = A_last...A_first,
//     v_c = sum_t (A_last...A_{t+1}) Bx_t.   One block (256 thr) per chunk.
// ---------------------------------------------------------------------------
__global__ __launch_bounds__(256) void k2_chunk(
    const float* __restrict__ A_ws, const float* __restrict__ Bx_ws,
    float* __restrict__ P_ws, float* __restrict__ v_ws)
{
  __shared__ float Ps[2][16][17];   // +1 pad
  __shared__ float vs[2][16];
  __shared__ float as[256];
  const int tid = threadIdx.x;
  const int i = tid >> 4, j = tid & 15;
  const int chunk = blockIdx.x;           // = b*NCH + c (chunks tile BS contiguously)
  const int tbase = chunk * CHUNK;

  Ps[0][i][j] = (i == j) ? 1.f : 0.f;
  if (tid < 16) vs[0][tid] = 0.f;
  as[tid] = A_ws[(size_t)tbase * 256 + tid];
  float bx = (tid < 16) ? Bx_ws[(size_t)tbase * DS + tid] : 0.f;
  __syncthreads();

  int cur = 0;
  for (int t = 0; t < CHUNK; ++t) {
    float a_next = 0.f, bx_next = 0.f;
    if (t < CHUNK - 1) {
      a_next = A_ws[(size_t)(tbase + t + 1) * 256 + tid];
      if (tid < 16) bx_next = Bx_ws[(size_t)(tbase + t + 1) * DS + tid];
    }
    float acc = 0.f;
    #pragma unroll
    for (int k = 0; k < 16; ++k)
      acc += as[i * 16 + k] * Ps[cur][k][j];
    float vacc = 0.f;
    if (tid < 16) {
      #pragma unroll
      for (int k = 0; k < 16; ++k)
        vacc += as[tid * 16 + k] * vs[cur][k];
      vacc += bx;
    }
    __syncthreads();
    Ps[cur ^ 1][i][j] = acc;
    if (tid < 16) vs[cur ^ 1][tid] = vacc;
    as[tid] = a_next;
    bx = bx_next;
    cur ^= 1;
    __syncthreads();
  }
  P_ws[(size_t)chunk * 256 + tid] = Ps[cur][i][j];
  if (tid < 16) v_ws[(size_t)chunk * DS + tid] = vs[cur][tid];
}

// ---------------------------------------------------------------------------
// K3: serial boundary scan across chunks (8 batches x 16 lanes = 128 thr,
// one block).  Writes the ENTERING state of every chunk.
// ---------------------------------------------------------------------------
__global__ __launch_bounds__(128) void k3_boundary(
    const float* __restrict__ P_ws, const float* __restrict__ v_ws,
    float* __restrict__ hb_ws)
{
  const int tid = threadIdx.x;
  const int b = tid >> 4;
  const int r = tid & 15;
  float h = 0.f;

  const float4* Pr = (const float4*)&P_ws[(size_t)(b * NCH) * 256 + r * 16];
  float4 c0 = Pr[0], c1 = Pr[1], c2 = Pr[2], c3 = Pr[3];
  float vc = v_ws[(size_t)(b * NCH) * DS + r];

  for (int c = 0; c < NCH; ++c) {
    const int chunk = b * NCH + c;
    float4 n0 = c0, n1 = c1, n2 = c2, n3 = c3; float nv = 0.f;
    if (c < NCH - 1) { // prefetch next chunk's row (independent of h)
      const float4* Pn = (const float4*)&P_ws[(size_t)(chunk + 1) * 256 + r * 16];
      n0 = Pn[0]; n1 = Pn[1]; n2 = Pn[2]; n3 = Pn[3];
      nv = v_ws[(size_t)(chunk + 1) * DS + r];
    }
    hb_ws[(size_t)chunk * DS + r] = h;
    float acc = vc;
    acc += c0.x*__shfl(h, 0,16) + c0.y*__shfl(h, 1,16) + c0.z*__shfl(h, 2,16) + c0.w*__shfl(h, 3,16);
    acc += c1.x*__shfl(h, 4,16) + c1.y*__shfl(h, 5,16) + c1.z*__shfl(h, 6,16) + c1.w*__shfl(h, 7,16);
    acc += c2.x*__shfl(h, 8,16) + c2.y*__shfl(h, 9,16) + c2.z*__shfl(h,10,16) + c2.w*__shfl(h,11,16);
    acc += c3.x*__shfl(h,12,16) + c3.y*__shfl(h,13,16) + c3.z*__shfl(h,14,16) + c3.w*__shfl(h,15,16);
    h = acc;
    c0 = n0; c1 = n1; c2 = n2; c3 = n3; vc = nv;
  }
}

// ---------------------------------------------------------------------------
// K4: replay scan within each chunk from its boundary state; emit all h_t.
// 64 threads = 4 groups of 16 lanes, one chunk per group. 4-deep prefetch.
// ---------------------------------------------------------------------------
__global__ __launch_bounds__(64) void k4_hs(
    const float* __restrict__ A_ws, const float* __restrict__ Bx_ws,
    const float* __restrict__ hb_ws, float* __restrict__ hs_ws)
{
  const int tid = threadIdx.x;
  const int g = tid >> 4;
  const int r = tid & 15;
  const int chunk = blockIdx.x * 4 + g;
  const int tbase = chunk * CHUNK;

  float h = hb_ws[(size_t)chunk * DS + r];
  float4 pa[4][4];
  float pbx[4];
  #pragma unroll
  for (int s = 0; s < 4; ++s) {
    const float4* Arow = (const float4*)&A_ws[(size_t)(tbase + s) * 256 + r * 16];
    pa[s][0] = Arow[0]; pa[s][1] = Arow[1]; pa[s][2] = Arow[2]; pa[s][3] = Arow[3];
    pbx[s] = Bx_ws[(size_t)(tbase + s) * DS + r];
  }

  for (int t = 0; t < CHUNK; t += 4) {
    #pragma unroll
    for (int u = 0; u < 4; ++u) {
      const int tt = t + u;
      float4 q0 = pa[u][0], q1 = pa[u][1], q2 = pa[u][2], q3 = pa[u][3];
      float acc = pbx[u];
      if (tt + 4 < CHUNK) { // refill slot (independent of h -> latency hidden)
        const float4* Arow = (const float4*)&A_ws[(size_t)(tbase + tt + 4) * 256 + r * 16];
        pa[u][0] = Arow[0]; pa[u][1] = Arow[1]; pa[u][2] = Arow[2]; pa[u][3] = Arow[3];
        pbx[u] = Bx_ws[(size_t)(tbase + tt + 4) * DS + r];
      }
      acc += q0.x*__shfl(h, 0,16) + q0.y*__shfl(h, 1,16) + q0.z*__shfl(h, 2,16) + q0.w*__shfl(h, 3,16);
      acc += q1.x*__shfl(h, 4,16) + q1.y*__shfl(h, 5,16) + q1.z*__shfl(h, 6,16) + q1.w*__shfl(h, 7,16);
      acc += q2.x*__shfl(h, 8,16) + q2.y*__shfl(h, 9,16) + q2.z*__shfl(h,10,16) + q2.w*__shfl(h,11,16);
      acc += q3.x*__shfl(h,12,16) + q3.y*__shfl(h,13,16) + q3.z*__shfl(h,14,16) + q3.w*__shfl(h,15,16);
      hs_ws[(size_t)(tbase + tt) * DS + r] = acc;
      h = acc;
    }
  }
}

// ---------------------------------------------------------------------------
// K5: fused output: out[t,d] = sum_n h[t,n] * (x_t . W_C[:,n*64+d] + b_C).
// Wave w owns t in [16w,16w+16), lane = d; out cells owned exclusively.
// ---------------------------------------------------------------------------
__global__ __launch_bounds__(256) void k5_out(
    const float* __restrict__ x,
    const float* __restrict__ WC, const float* __restrict__ bC,
    const float* __restrict__ hs_ws, float* __restrict__ out)
{
  __shared__ __align__(16) float xs[64][64];
  __shared__ __align__(16) float hsh[64][16];
  const int tid = threadIdx.x;
  const int t0  = blockIdx.x * 64;

  { // stage x tile
    const float4* xg = (const float4*)(x + (size_t)t0 * DM);
    float4* xsv = (float4*)&xs[0][0];
    #pragma unroll
    for (int i = 0; i < 4; ++i) xsv[tid + 256 * i] = xg[tid + 256 * i];
  }
  { // stage h tile (64x16 = 1024 floats = 256 float4)
    const float4* hg = (const float4*)(hs_ws + (size_t)t0 * DS);
    float4* hv = (float4*)&hsh[0][0];
    hv[tid] = hg[tid];
  }
  __syncthreads();

  const int lane = tid & 63;
  const int wave = tid >> 6;
  const int tb = wave * 16;

  float acc[16];
  #pragma unroll
  for (int u = 0; u < 16; ++u) acc[u] = 0.f;

  for (int n = 0; n < 16; ++n) {
    float col[64];
    #pragma unroll
    for (int e = 0; e < 64; ++e) col[e] = WC[e * 1024 + n * 64 + lane];
    const float bias = bC[n * 64 + lane];
    #pragma unroll
    for (int u = 0; u < 16; ++u) {
      const int t = tb + u;
      acc[u] += hsh[t][n] * dot64(&xs[t][0], col, bias);
    }
  }

  #pragma unroll
  for (int u = 0; u < 16; ++u)
    out[(size_t)(t0 + tb + u) * DM + lane] = acc[u];
}

// ---------------------------------------------------------------------------
extern "C" void kernel_launch(void* const* d_in, const int* in_sizes, int n_in,
                              void* d_out, int out_size, void* d_ws, size_t ws_size,
                              hipStream_t stream) {
  const float* x  = (const float*)d_in[0];
  const float* WA = (const float*)d_in[1];
  const float* bA = (const float*)d_in[2];
  const float* WB = (const float*)d_in[3];
  const float* bB = (const float*)d_in[4];
  const float* WC = (const float*)d_in[5];
  const float* bC = (const float*)d_in[6];
  float* out = (float*)d_out;

  float* ws    = (float*)d_ws;
  float* A_ws  = ws;                              // 32768*256 = 8,388,608
  float* Bx_ws = A_ws  + (size_t)BS * 256;        //   524,288
  float* P_ws  = Bx_ws + (size_t)BS * DS;         //   131,072
  float* v_ws  = P_ws  + (size_t)NCH_TOT * 256;   //     8,192
  float* hb_ws = v_ws  + (size_t)NCH_TOT * DS;    //     8,192
  float* hs_ws = hb_ws + (size_t)NCH_TOT * DS;    //   524,288
  // total ~38.3 MB of d_ws

  k1_params  <<<BS / 64,   256, 0, stream>>>(x, WA, bA, WB, bB, A_ws, Bx_ws);
  k2_chunk   <<<NCH_TOT,   256, 0, stream>>>(A_ws, Bx_ws, P_ws, v_ws);
  k3_boundary<<<1,         128, 0, stream>>>(P_ws, v_ws, hb_ws);
  k4_hs      <<<NCH_TOT/4,  64, 0, stream>>>(A_ws, Bx_ws, hb_ws, hs_ws);
  k5_out     <<<BS / 64,   256, 0, stream>>>(x, WC, bC, hs_ws, out);
}

// Round 2
// 1252.393 us; speedup vs baseline: 2.4793x; 2.4793x over previous
//
#include <hip/hip_runtime.h>

// Problem constants (B=8, S=4096, D=64, ds=16)
#define BATCH   8
#define SEQ     4096
#define DM      64
#define DS      16
#define BS      (BATCH*SEQ)      // 32768 timesteps
#define CHUNK   64               // scan chunk length
#define NCH     (SEQ/CHUNK)      // 64 chunks per batch
#define NCH_TOT (BATCH*NCH)      // 512 chunks total

// ---------------------------------------------------------------------------
// K1: per-timestep selective params.  A_t (16x16) and Bx_t (16) for 64
// timesteps per block.  256 threads.  All weight tiles bounded to 16 regs.
// ---------------------------------------------------------------------------
__global__ __launch_bounds__(256, 4) void k1_params(
    const float* __restrict__ x,
    const float* __restrict__ WA, const float* __restrict__ bA,
    const float* __restrict__ WB, const float* __restrict__ bB,
    float* __restrict__ A_ws, float* __restrict__ Bx_ws)
{
  __shared__ __align__(16) float xs[64][64];
  const int tid = threadIdx.x;
  const int t0  = blockIdx.x * 64;

  { // stage x tile (64x64 fp32 = 16KB), coalesced float4
    const float4* xg = (const float4*)(x + (size_t)t0 * DM);
    float4* xsv = (float4*)&xs[0][0];
    #pragma unroll
    for (int i = 0; i < 4; ++i) xsv[tid + 256 * i] = xg[tid + 256 * i];
  }
  __syncthreads();

  // ---- A: thread tid owns W_A column tid; t tiled by 16, e tiled by 16 ----
  {
    const float biasA = bA[tid];
    #pragma unroll 1
    for (int tg = 0; tg < 4; ++tg) {
      float acc[16];
      #pragma unroll
      for (int u = 0; u < 16; ++u) acc[u] = biasA;
      #pragma unroll 1
      for (int et = 0; et < 4; ++et) {
        float col[16];
        #pragma unroll
        for (int k = 0; k < 16; ++k) col[k] = WA[(et * 16 + k) * 256 + tid];
        #pragma unroll
        for (int u = 0; u < 16; ++u) {
          const float* xr = &xs[tg * 16 + u][et * 16];
          float4 xa = *(const float4*)(xr + 0);
          float4 xb = *(const float4*)(xr + 4);
          float4 xc = *(const float4*)(xr + 8);
          float4 xd = *(const float4*)(xr + 12);
          float p0 = xa.x*col[0]  + xa.y*col[1]  + xa.z*col[2]  + xa.w*col[3];
          float p1 = xb.x*col[4]  + xb.y*col[5]  + xb.z*col[6]  + xb.w*col[7];
          float p2 = xc.x*col[8]  + xc.y*col[9]  + xc.z*col[10] + xc.w*col[11];
          float p3 = xd.x*col[12] + xd.y*col[13] + xd.z*col[14] + xd.w*col[15];
          acc[u] += (p0 + p1) + (p2 + p3);
        }
      }
      #pragma unroll
      for (int u = 0; u < 16; ++u)
        A_ws[(size_t)(t0 + tg * 16 + u) * 256 + tid] = acc[u];
    }
  }

  // ---- Bx: quadratic form.  wave handles n = p*4 + wave, lane = d.
  //      partial dot accumulated over e-tiles (linearity), then *x, reduce.
  const int lane = tid & 63;
  const int wave = tid >> 6;
  #pragma unroll 1
  for (int p = 0; p < 4; ++p) {
    const int n = p * 4 + wave;
    const float biasB = bB[n * 64 + lane];
    #pragma unroll 1
    for (int tg = 0; tg < 4; ++tg) {
      float pacc[16];
      #pragma unroll
      for (int u = 0; u < 16; ++u) pacc[u] = biasB;
      #pragma unroll 1
      for (int et = 0; et < 4; ++et) {
        float col[16];
        #pragma unroll
        for (int k = 0; k < 16; ++k) col[k] = WB[(et * 16 + k) * 1024 + n * 64 + lane];
        #pragma unroll
        for (int u = 0; u < 16; ++u) {
          const float* xr = &xs[tg * 16 + u][et * 16];
          float4 xa = *(const float4*)(xr + 0);
          float4 xb = *(const float4*)(xr + 4);
          float4 xc = *(const float4*)(xr + 8);
          float4 xd = *(const float4*)(xr + 12);
          float p0 = xa.x*col[0]  + xa.y*col[1]  + xa.z*col[2]  + xa.w*col[3];
          float p1 = xb.x*col[4]  + xb.y*col[5]  + xb.z*col[6]  + xb.w*col[7];
          float p2 = xc.x*col[8]  + xc.y*col[9]  + xc.z*col[10] + xc.w*col[11];
          float p3 = xd.x*col[12] + xd.y*col[13] + xd.z*col[14] + xd.w*col[15];
          pacc[u] += (p0 + p1) + (p2 + p3);
        }
      }
      #pragma unroll
      for (int u = 0; u < 16; ++u) {
        const int t = tg * 16 + u;
        float contrib = pacc[u] * xs[t][lane];
        #pragma unroll
        for (int off = 32; off; off >>= 1)
          contrib += __shfl_xor(contrib, off, 64);
        if (lane == 0) Bx_ws[(size_t)(t0 + t) * DS + n] = contrib;
      }
    }
  }
}

// ---------------------------------------------------------------------------
// K2: per-chunk cumulative transition:  P_c = A_last...A_first,
//     v_c = sum_t (A_last...A_{t+1}) Bx_t.   One block (256 thr) per chunk.
// ---------------------------------------------------------------------------
__global__ __launch_bounds__(256) void k2_chunk(
    const float* __restrict__ A_ws, const float* __restrict__ Bx_ws,
    float* __restrict__ P_ws, float* __restrict__ v_ws)
{
  __shared__ float Ps[2][16][17];   // +1 pad
  __shared__ float vs[2][16];
  __shared__ float as[256];
  const int tid = threadIdx.x;
  const int i = tid >> 4, j = tid & 15;
  const int chunk = blockIdx.x;
  const int tbase = chunk * CHUNK;

  Ps[0][i][j] = (i == j) ? 1.f : 0.f;
  if (tid < 16) vs[0][tid] = 0.f;
  as[tid] = A_ws[(size_t)tbase * 256 + tid];
  float bx = (tid < 16) ? Bx_ws[(size_t)tbase * DS + tid] : 0.f;
  __syncthreads();

  int cur = 0;
  for (int t = 0; t < CHUNK; ++t) {
    float a_next = 0.f, bx_next = 0.f;
    if (t < CHUNK - 1) {
      a_next = A_ws[(size_t)(tbase + t + 1) * 256 + tid];
      if (tid < 16) bx_next = Bx_ws[(size_t)(tbase + t + 1) * DS + tid];
    }
    float acc = 0.f;
    #pragma unroll
    for (int k = 0; k < 16; ++k)
      acc += as[i * 16 + k] * Ps[cur][k][j];
    float vacc = 0.f;
    if (tid < 16) {
      #pragma unroll
      for (int k = 0; k < 16; ++k)
        vacc += as[tid * 16 + k] * vs[cur][k];
      vacc += bx;
    }
    __syncthreads();
    Ps[cur ^ 1][i][j] = acc;
    if (tid < 16) vs[cur ^ 1][tid] = vacc;
    as[tid] = a_next;
    bx = bx_next;
    cur ^= 1;
    __syncthreads();
  }
  P_ws[(size_t)chunk * 256 + tid] = Ps[cur][i][j];
  if (tid < 16) v_ws[(size_t)chunk * DS + tid] = vs[cur][tid];
}

// ---------------------------------------------------------------------------
// K3: serial boundary scan across chunks (8 batches x 16 lanes = 128 thr,
// one block).  Writes the ENTERING state of every chunk.
// ---------------------------------------------------------------------------
__global__ __launch_bounds__(128) void k3_boundary(
    const float* __restrict__ P_ws, const float* __restrict__ v_ws,
    float* __restrict__ hb_ws)
{
  const int tid = threadIdx.x;
  const int b = tid >> 4;
  const int r = tid & 15;
  float h = 0.f;

  const float4* Pr = (const float4*)&P_ws[(size_t)(b * NCH) * 256 + r * 16];
  float4 c0 = Pr[0], c1 = Pr[1], c2 = Pr[2], c3 = Pr[3];
  float vc = v_ws[(size_t)(b * NCH) * DS + r];

  for (int c = 0; c < NCH; ++c) {
    const int chunk = b * NCH + c;
    float4 n0 = c0, n1 = c1, n2 = c2, n3 = c3; float nv = 0.f;
    if (c < NCH - 1) {
      const float4* Pn = (const float4*)&P_ws[(size_t)(chunk + 1) * 256 + r * 16];
      n0 = Pn[0]; n1 = Pn[1]; n2 = Pn[2]; n3 = Pn[3];
      nv = v_ws[(size_t)(chunk + 1) * DS + r];
    }
    hb_ws[(size_t)chunk * DS + r] = h;
    float acc = vc;
    acc += c0.x*__shfl(h, 0,16) + c0.y*__shfl(h, 1,16) + c0.z*__shfl(h, 2,16) + c0.w*__shfl(h, 3,16);
    acc += c1.x*__shfl(h, 4,16) + c1.y*__shfl(h, 5,16) + c1.z*__shfl(h, 6,16) + c1.w*__shfl(h, 7,16);
    acc += c2.x*__shfl(h, 8,16) + c2.y*__shfl(h, 9,16) + c2.z*__shfl(h,10,16) + c2.w*__shfl(h,11,16);
    acc += c3.x*__shfl(h,12,16) + c3.y*__shfl(h,13,16) + c3.z*__shfl(h,14,16) + c3.w*__shfl(h,15,16);
    h = acc;
    c0 = n0; c1 = n1; c2 = n2; c3 = n3; vc = nv;
  }
}

// ---------------------------------------------------------------------------
// K4: replay scan within each chunk from its boundary state; emit all h_t.
// 64 threads = 4 groups of 16 lanes, one chunk per group. 4-deep prefetch.
// ---------------------------------------------------------------------------
__global__ __launch_bounds__(64) void k4_hs(
    const float* __restrict__ A_ws, const float* __restrict__ Bx_ws,
    const float* __restrict__ hb_ws, float* __restrict__ hs_ws)
{
  const int tid = threadIdx.x;
  const int g = tid >> 4;
  const int r = tid & 15;
  const int chunk = blockIdx.x * 4 + g;
  const int tbase = chunk * CHUNK;

  float h = hb_ws[(size_t)chunk * DS + r];
  float4 pa[4][4];
  float pbx[4];
  #pragma unroll
  for (int s = 0; s < 4; ++s) {
    const float4* Arow = (const float4*)&A_ws[(size_t)(tbase + s) * 256 + r * 16];
    pa[s][0] = Arow[0]; pa[s][1] = Arow[1]; pa[s][2] = Arow[2]; pa[s][3] = Arow[3];
    pbx[s] = Bx_ws[(size_t)(tbase + s) * DS + r];
  }

  for (int t = 0; t < CHUNK; t += 4) {
    #pragma unroll
    for (int u = 0; u < 4; ++u) {
      const int tt = t + u;
      float4 q0 = pa[u][0], q1 = pa[u][1], q2 = pa[u][2], q3 = pa[u][3];
      float acc = pbx[u];
      if (tt + 4 < CHUNK) {
        const float4* Arow = (const float4*)&A_ws[(size_t)(tbase + tt + 4) * 256 + r * 16];
        pa[u][0] = Arow[0]; pa[u][1] = Arow[1]; pa[u][2] = Arow[2]; pa[u][3] = Arow[3];
        pbx[u] = Bx_ws[(size_t)(tbase + tt + 4) * DS + r];
      }
      acc += q0.x*__shfl(h, 0,16) + q0.y*__shfl(h, 1,16) + q0.z*__shfl(h, 2,16) + q0.w*__shfl(h, 3,16);
      acc += q1.x*__shfl(h, 4,16) + q1.y*__shfl(h, 5,16) + q1.z*__shfl(h, 6,16) + q1.w*__shfl(h, 7,16);
      acc += q2.x*__shfl(h, 8,16) + q2.y*__shfl(h, 9,16) + q2.z*__shfl(h,10,16) + q2.w*__shfl(h,11,16);
      acc += q3.x*__shfl(h,12,16) + q3.y*__shfl(h,13,16) + q3.z*__shfl(h,14,16) + q3.w*__shfl(h,15,16);
      hs_ws[(size_t)(tbase + tt) * DS + r] = acc;
      h = acc;
    }
  }
}

// ---------------------------------------------------------------------------
// K5: fused output: out[t,d] = sum_n h[t,n] * (x_t . W_C[:,n*64+d] + b_C).
// Wave w owns t in [16w,16w+16), lane = d.  n tiled by 4, e tiled by 16:
// col working set = 4x16 regs, acc[16].  Bias handled in a prologue.
// ---------------------------------------------------------------------------
__global__ __launch_bounds__(256, 4) void k5_out(
    const float* __restrict__ x,
    const float* __restrict__ WC, const float* __restrict__ bC,
    const float* __restrict__ hs_ws, float* __restrict__ out)
{
  __shared__ __align__(16) float xs[64][64];
  __shared__ __align__(16) float hsh[64][16];
  const int tid = threadIdx.x;
  const int t0  = blockIdx.x * 64;

  { // stage x tile
    const float4* xg = (const float4*)(x + (size_t)t0 * DM);
    float4* xsv = (float4*)&xs[0][0];
    #pragma unroll
    for (int i = 0; i < 4; ++i) xsv[tid + 256 * i] = xg[tid + 256 * i];
  }
  { // stage h tile (64x16 = 1024 floats = 256 float4)
    const float4* hg = (const float4*)(hs_ws + (size_t)t0 * DS);
    float4* hv = (float4*)&hsh[0][0];
    hv[tid] = hg[tid];
  }
  __syncthreads();

  const int lane = tid & 63;
  const int wave = tid >> 6;
  const int tb = wave * 16;

  float acc[16];

  { // prologue: acc[u] = sum_n h[t,n] * bC[n*64+lane]
    float bcol[16];
    #pragma unroll
    for (int n = 0; n < 16; ++n) bcol[n] = bC[n * 64 + lane];
    #pragma unroll
    for (int u = 0; u < 16; ++u) {
      const int t = tb + u;
      float4 h0 = *(const float4*)&hsh[t][0];
      float4 h1 = *(const float4*)&hsh[t][4];
      float4 h2 = *(const float4*)&hsh[t][8];
      float4 h3 = *(const float4*)&hsh[t][12];
      float b0 = h0.x*bcol[0]  + h0.y*bcol[1]  + h0.z*bcol[2]  + h0.w*bcol[3];
      float b1 = h1.x*bcol[4]  + h1.y*bcol[5]  + h1.z*bcol[6]  + h1.w*bcol[7];
      float b2 = h2.x*bcol[8]  + h2.y*bcol[9]  + h2.z*bcol[10] + h2.w*bcol[11];
      float b3 = h3.x*bcol[12] + h3.y*bcol[13] + h3.z*bcol[14] + h3.w*bcol[15];
      acc[u] = (b0 + b1) + (b2 + b3);
    }
  }

  #pragma unroll 1
  for (int nq = 0; nq < 4; ++nq) {
    #pragma unroll 1
    for (int et = 0; et < 4; ++et) {
      float colq[4][16];
      #pragma unroll
      for (int nn = 0; nn < 4; ++nn)
        #pragma unroll
        for (int k = 0; k < 16; ++k)
          colq[nn][k] = WC[(et * 16 + k) * 1024 + (nq * 4 + nn) * 64 + lane];
      #pragma unroll
      for (int u = 0; u < 16; ++u) {
        const int t = tb + u;
        float4 hv = *(const float4*)&hsh[t][nq * 4];
        const float* xr = &xs[t][et * 16];
        float4 xa = *(const float4*)(xr + 0);
        float4 xb = *(const float4*)(xr + 4);
        float4 xc = *(const float4*)(xr + 8);
        float4 xd = *(const float4*)(xr + 12);
        float hn[4] = {hv.x, hv.y, hv.z, hv.w};
        #pragma unroll
        for (int nn = 0; nn < 4; ++nn) {
          float p0 = xa.x*colq[nn][0]  + xa.y*colq[nn][1]  + xa.z*colq[nn][2]  + xa.w*colq[nn][3];
          float p1 = xb.x*colq[nn][4]  + xb.y*colq[nn][5]  + xb.z*colq[nn][6]  + xb.w*colq[nn][7];
          float p2 = xc.x*colq[nn][8]  + xc.y*colq[nn][9]  + xc.z*colq[nn][10] + xc.w*colq[nn][11];
          float p3 = xd.x*colq[nn][12] + xd.y*colq[nn][13] + xd.z*colq[nn][14] + xd.w*colq[nn][15];
          acc[u] += hn[nn] * ((p0 + p1) + (p2 + p3));
        }
      }
    }
  }

  #pragma unroll
  for (int u = 0; u < 16; ++u)
    out[(size_t)(t0 + tb + u) * DM + lane] = acc[u];
}

// ---------------------------------------------------------------------------
extern "C" void kernel_launch(void* const* d_in, const int* in_sizes, int n_in,
                              void* d_out, int out_size, void* d_ws, size_t ws_size,
                              hipStream_t stream) {
  const float* x  = (const float*)d_in[0];
  const float* WA = (const float*)d_in[1];
  const float* bA = (const float*)d_in[2];
  const float* WB = (const float*)d_in[3];
  const float* bB = (const float*)d_in[4];
  const float* WC = (const float*)d_in[5];
  const float* bC = (const float*)d_in[6];
  float* out = (float*)d_out;

  float* ws    = (float*)d_ws;
  float* A_ws  = ws;                              // 32768*256 = 8,388,608
  float* Bx_ws = A_ws  + (size_t)BS * 256;        //   524,288
  float* P_ws  = Bx_ws + (size_t)BS * DS;         //   131,072
  float* v_ws  = P_ws  + (size_t)NCH_TOT * 256;   //     8,192
  float* hb_ws = v_ws  + (size_t)NCH_TOT * DS;    //     8,192
  float* hs_ws = hb_ws + (size_t)NCH_TOT * DS;    //   524,288

  k1_params  <<<BS / 64,   256, 0, stream>>>(x, WA, bA, WB, bB, A_ws, Bx_ws);
  k2_chunk   <<<NCH_TOT,   256, 0, stream>>>(A_ws, Bx_ws, P_ws, v_ws);
  k3_boundary<<<1,         128, 0, stream>>>(P_ws, v_ws, hb_ws);
  k4_hs      <<<NCH_TOT/4,  64, 0, stream>>>(A_ws, Bx_ws, hb_ws, hs_ws);
  k5_out     <<<BS / 64,   256, 0, stream>>>(x, WC, bC, hs_ws, out);
}

// Round 3
// 396.371 us; speedup vs baseline: 7.8338x; 3.1596x over previous
//
#include <hip/hip_runtime.h>

// Problem constants (B=8, S=4096, D=64, ds=16)
#define BATCH   8
#define SEQ     4096
#define DM      64
#define DS      16
#define BS      (BATCH*SEQ)      // 32768 timesteps
#define CHUNK   64               // scan chunk length
#define NCH     (SEQ/CHUNK)      // 64 chunks per batch
#define NCH_TOT (BATCH*NCH)      // 512 chunks total

// ---------------------------------------------------------------------------
// K1: lane = timestep.  Block = 512 thr = 8 waves over one 64-t tile:
// waves 0..3 compute A (64 j-cols each), waves 4..7 compute Bx (4 n each).
// Weights are wave-uniform -> SGPR loads; x read per-lane from padded LDS.
// ---------------------------------------------------------------------------
__global__ __launch_bounds__(512) void k1_params(
    const float* __restrict__ x,
    const float* __restrict__ WA, const float* __restrict__ bA,
    const float* __restrict__ WB, const float* __restrict__ bB,
    float* __restrict__ A_ws, float* __restrict__ Bx_ws)
{
  __shared__ float xs[64][65];   // +1 pad: row reads are 2-way (free)
  const int tid = threadIdx.x;
  const int t0  = blockIdx.x * 64;

  { // stage + transpose x tile (coalesced float4 in, scalar LDS out)
    const float4* xg = (const float4*)(x + (size_t)t0 * DM);
    #pragma unroll
    for (int i = 0; i < 2; ++i) {
      const int f4 = tid + 512 * i;          // 0..1023
      float4 v = xg[f4];
      const int t = (4 * f4) >> 6;
      const int e = (4 * f4) & 63;
      xs[t][e] = v.x; xs[t][e + 1] = v.y; xs[t][e + 2] = v.z; xs[t][e + 3] = v.w;
    }
  }
  __syncthreads();

  const int L  = tid & 63;                   // lane = local timestep
  const int w  = __builtin_amdgcn_readfirstlane(tid >> 6); // uniform wave id
  const int tt = t0 + L;

  if (w < 4) {
    // ---- A quarter: j in [w*64, w*64+64) ----
    const int j0 = w * 64;
    #pragma unroll 1
    for (int jt = 0; jt < 4; ++jt) {
      const int jb = j0 + jt * 16;
      float acc[16];
      #pragma unroll
      for (int k = 0; k < 16; ++k) acc[k] = bA[jb + k];
      #pragma unroll 4
      for (int e = 0; e < 64; ++e) {
        const float xe = xs[L][e];
        const float* wr = WA + e * 256 + jb;   // uniform address
        #pragma unroll
        for (int k = 0; k < 16; ++k) acc[k] = fmaf(xe, wr[k], acc[k]);
      }
      float* dst = A_ws + (size_t)tt * 256 + jb;
      #pragma unroll
      for (int q = 0; q < 4; ++q)
        ((float4*)dst)[q] = make_float4(acc[4*q], acc[4*q+1], acc[4*q+2], acc[4*q+3]);
    }
  } else {
    // ---- Bx group: n in [(w-4)*4, +4) ----
    const int n0 = (w - 4) * 4;
    #pragma unroll 1
    for (int nn = 0; nn < 4; ++nn) {
      const int n = n0 + nn;
      float y[64];
      #pragma unroll
      for (int d = 0; d < 64; ++d) y[d] = bB[n * 64 + d];
      #pragma unroll 2
      for (int e = 0; e < 64; ++e) {
        const float xe = xs[L][e];
        const float* wr = WB + e * 1024 + n * 64;   // uniform address
        #pragma unroll
        for (int d = 0; d < 64; ++d) y[d] = fmaf(xe, wr[d], y[d]);
      }
      float bx = 0.f;
      #pragma unroll
      for (int d = 0; d < 64; ++d) bx = fmaf(xs[L][d], y[d], bx);
      Bx_ws[(size_t)tt * DS + n] = bx;
    }
  }
}

// ---------------------------------------------------------------------------
// K2: per-chunk cumulative transition:  P_c = A_last...A_first,
//     v_c = sum_t (A_last...A_{t+1}) Bx_t.   One block (256 thr) per chunk.
// ---------------------------------------------------------------------------
__global__ __launch_bounds__(256) void k2_chunk(
    const float* __restrict__ A_ws, const float* __restrict__ Bx_ws,
    float* __restrict__ P_ws, float* __restrict__ v_ws)
{
  __shared__ float Ps[2][16][17];   // +1 pad
  __shared__ float vs[2][16];
  __shared__ float as[256];
  const int tid = threadIdx.x;
  const int i = tid >> 4, j = tid & 15;
  const int chunk = blockIdx.x;
  const int tbase = chunk * CHUNK;

  Ps[0][i][j] = (i == j) ? 1.f : 0.f;
  if (tid < 16) vs[0][tid] = 0.f;
  as[tid] = A_ws[(size_t)tbase * 256 + tid];
  float bx = (tid < 16) ? Bx_ws[(size_t)tbase * DS + tid] : 0.f;
  __syncthreads();

  int cur = 0;
  for (int t = 0; t < CHUNK; ++t) {
    float a_next = 0.f, bx_next = 0.f;
    if (t < CHUNK - 1) {
      a_next = A_ws[(size_t)(tbase + t + 1) * 256 + tid];
      if (tid < 16) bx_next = Bx_ws[(size_t)(tbase + t + 1) * DS + tid];
    }
    float acc = 0.f;
    #pragma unroll
    for (int k = 0; k < 16; ++k)
      acc += as[i * 16 + k] * Ps[cur][k][j];
    float vacc = 0.f;
    if (tid < 16) {
      #pragma unroll
      for (int k = 0; k < 16; ++k)
        vacc += as[tid * 16 + k] * vs[cur][k];
      vacc += bx;
    }
    __syncthreads();
    Ps[cur ^ 1][i][j] = acc;
    if (tid < 16) vs[cur ^ 1][tid] = vacc;
    as[tid] = a_next;
    bx = bx_next;
    cur ^= 1;
    __syncthreads();
  }
  P_ws[(size_t)chunk * 256 + tid] = Ps[cur][i][j];
  if (tid < 16) v_ws[(size_t)chunk * DS + tid] = vs[cur][tid];
}

// ---------------------------------------------------------------------------
// K3: serial boundary scan across chunks (8 batches x 16 lanes = 128 thr,
// one block).  Writes the ENTERING state of every chunk.
// ---------------------------------------------------------------------------
__global__ __launch_bounds__(128) void k3_boundary(
    const float* __restrict__ P_ws, const float* __restrict__ v_ws,
    float* __restrict__ hb_ws)
{
  const int tid = threadIdx.x;
  const int b = tid >> 4;
  const int r = tid & 15;
  float h = 0.f;

  const float4* Pr = (const float4*)&P_ws[(size_t)(b * NCH) * 256 + r * 16];
  float4 c0 = Pr[0], c1 = Pr[1], c2 = Pr[2], c3 = Pr[3];
  float vc = v_ws[(size_t)(b * NCH) * DS + r];

  for (int c = 0; c < NCH; ++c) {
    const int chunk = b * NCH + c;
    float4 n0 = c0, n1 = c1, n2 = c2, n3 = c3; float nv = 0.f;
    if (c < NCH - 1) {
      const float4* Pn = (const float4*)&P_ws[(size_t)(chunk + 1) * 256 + r * 16];
      n0 = Pn[0]; n1 = Pn[1]; n2 = Pn[2]; n3 = Pn[3];
      nv = v_ws[(size_t)(chunk + 1) * DS + r];
    }
    hb_ws[(size_t)chunk * DS + r] = h;
    float acc = vc;
    acc += c0.x*__shfl(h, 0,16) + c0.y*__shfl(h, 1,16) + c0.z*__shfl(h, 2,16) + c0.w*__shfl(h, 3,16);
    acc += c1.x*__shfl(h, 4,16) + c1.y*__shfl(h, 5,16) + c1.z*__shfl(h, 6,16) + c1.w*__shfl(h, 7,16);
    acc += c2.x*__shfl(h, 8,16) + c2.y*__shfl(h, 9,16) + c2.z*__shfl(h,10,16) + c2.w*__shfl(h,11,16);
    acc += c3.x*__shfl(h,12,16) + c3.y*__shfl(h,13,16) + c3.z*__shfl(h,14,16) + c3.w*__shfl(h,15,16);
    h = acc;
    c0 = n0; c1 = n1; c2 = n2; c3 = n3; vc = nv;
  }
}

// ---------------------------------------------------------------------------
// K4: replay scan within each chunk from its boundary state; emit all h_t.
// 64 threads = 4 groups of 16 lanes, one chunk per group. 4-deep prefetch.
// ---------------------------------------------------------------------------
__global__ __launch_bounds__(64) void k4_hs(
    const float* __restrict__ A_ws, const float* __restrict__ Bx_ws,
    const float* __restrict__ hb_ws, float* __restrict__ hs_ws)
{
  const int tid = threadIdx.x;
  const int g = tid >> 4;
  const int r = tid & 15;
  const int chunk = blockIdx.x * 4 + g;
  const int tbase = chunk * CHUNK;

  float h = hb_ws[(size_t)chunk * DS + r];
  float4 pa[4][4];
  float pbx[4];
  #pragma unroll
  for (int s = 0; s < 4; ++s) {
    const float4* Arow = (const float4*)&A_ws[(size_t)(tbase + s) * 256 + r * 16];
    pa[s][0] = Arow[0]; pa[s][1] = Arow[1]; pa[s][2] = Arow[2]; pa[s][3] = Arow[3];
    pbx[s] = Bx_ws[(size_t)(tbase + s) * DS + r];
  }

  for (int t = 0; t < CHUNK; t += 4) {
    #pragma unroll
    for (int u = 0; u < 4; ++u) {
      const int tt = t + u;
      float4 q0 = pa[u][0], q1 = pa[u][1], q2 = pa[u][2], q3 = pa[u][3];
      float acc = pbx[u];
      if (tt + 4 < CHUNK) {
        const float4* Arow = (const float4*)&A_ws[(size_t)(tbase + tt + 4) * 256 + r * 16];
        pa[u][0] = Arow[0]; pa[u][1] = Arow[1]; pa[u][2] = Arow[2]; pa[u][3] = Arow[3];
        pbx[u] = Bx_ws[(size_t)(tbase + tt + 4) * DS + r];
      }
      acc += q0.x*__shfl(h, 0,16) + q0.y*__shfl(h, 1,16) + q0.z*__shfl(h, 2,16) + q0.w*__shfl(h, 3,16);
      acc += q1.x*__shfl(h, 4,16) + q1.y*__shfl(h, 5,16) + q1.z*__shfl(h, 6,16) + q1.w*__shfl(h, 7,16);
      acc += q2.x*__shfl(h, 8,16) + q2.y*__shfl(h, 9,16) + q2.z*__shfl(h,10,16) + q2.w*__shfl(h,11,16);
      acc += q3.x*__shfl(h,12,16) + q3.y*__shfl(h,13,16) + q3.z*__shfl(h,14,16) + q3.w*__shfl(h,15,16);
      hs_ws[(size_t)(tbase + tt) * DS + r] = acc;
      h = acc;
    }
  }
}

// ---------------------------------------------------------------------------
// K5: lane = timestep.  Block = 256 thr = 4 waves over one 64-t tile,
// wave w owns d-range [w*16, w*16+16).  out[t,d] = sum_n h[t,n] *
// (bC[n*64+d] + sum_e x[t,e] WC[e, n*64+d]).  Weights wave-uniform.
// ---------------------------------------------------------------------------
__global__ __launch_bounds__(256) void k5_out(
    const float* __restrict__ x,
    const float* __restrict__ WC, const float* __restrict__ bC,
    const float* __restrict__ hs_ws, float* __restrict__ out)
{
  __shared__ float xs[64][65];
  __shared__ float hsh[64][17];
  const int tid = threadIdx.x;
  const int t0  = blockIdx.x * 64;

  { // stage + transpose x tile
    const float4* xg = (const float4*)(x + (size_t)t0 * DM);
    #pragma unroll
    for (int i = 0; i < 4; ++i) {
      const int f4 = tid + 256 * i;
      float4 v = xg[f4];
      const int t = (4 * f4) >> 6;
      const int e = (4 * f4) & 63;
      xs[t][e] = v.x; xs[t][e + 1] = v.y; xs[t][e + 2] = v.z; xs[t][e + 3] = v.w;
    }
    // stage h tile (64x16)
    const float4* hg = (const float4*)(hs_ws + (size_t)t0 * DS);
    float4 hv = hg[tid];
    const int t = (4 * tid) >> 4;
    const int n = (4 * tid) & 15;
    hsh[t][n] = hv.x; hsh[t][n + 1] = hv.y; hsh[t][n + 2] = hv.z; hsh[t][n + 3] = hv.w;
  }
  __syncthreads();

  const int L  = tid & 63;
  const int w  = __builtin_amdgcn_readfirstlane(tid >> 6);
  const int d0 = w * 16;

  float acc[16];
  #pragma unroll
  for (int k = 0; k < 16; ++k) acc[k] = 0.f;

  #pragma unroll 1
  for (int n = 0; n < 16; ++n) {
    const float hn = hsh[L][n];
    const float* bcr = bC + n * 64 + d0;          // uniform
    #pragma unroll
    for (int k = 0; k < 16; ++k) acc[k] = fmaf(hn, bcr[k], acc[k]);
    #pragma unroll 2
    for (int e = 0; e < 64; ++e) {
      const float p = hn * xs[L][e];
      const float* wr = WC + e * 1024 + n * 64 + d0;  // uniform
      #pragma unroll
      for (int k = 0; k < 16; ++k) acc[k] = fmaf(p, wr[k], acc[k]);
    }
  }

  float* dst = out + (size_t)(t0 + L) * DM + d0;
  #pragma unroll
  for (int q = 0; q < 4; ++q)
    ((float4*)dst)[q] = make_float4(acc[4*q], acc[4*q+1], acc[4*q+2], acc[4*q+3]);
}

// ---------------------------------------------------------------------------
extern "C" void kernel_launch(void* const* d_in, const int* in_sizes, int n_in,
                              void* d_out, int out_size, void* d_ws, size_t ws_size,
                              hipStream_t stream) {
  const float* x  = (const float*)d_in[0];
  const float* WA = (const float*)d_in[1];
  const float* bA = (const float*)d_in[2];
  const float* WB = (const float*)d_in[3];
  const float* bB = (const float*)d_in[4];
  const float* WC = (const float*)d_in[5];
  const float* bC = (const float*)d_in[6];
  float* out = (float*)d_out;

  float* ws    = (float*)d_ws;
  float* A_ws  = ws;                              // 32768*256 = 8,388,608
  float* Bx_ws = A_ws  + (size_t)BS * 256;        //   524,288
  float* P_ws  = Bx_ws + (size_t)BS * DS;         //   131,072
  float* v_ws  = P_ws  + (size_t)NCH_TOT * 256;   //     8,192
  float* hb_ws = v_ws  + (size_t)NCH_TOT * DS;    //     8,192
  float* hs_ws = hb_ws + (size_t)NCH_TOT * DS;    //   524,288

  k1_params  <<<BS / 64,   512, 0, stream>>>(x, WA, bA, WB, bB, A_ws, Bx_ws);
  k2_chunk   <<<NCH_TOT,   256, 0, stream>>>(A_ws, Bx_ws, P_ws, v_ws);
  k3_boundary<<<1,         128, 0, stream>>>(P_ws, v_ws, hb_ws);
  k4_hs      <<<NCH_TOT/4,  64, 0, stream>>>(A_ws, Bx_ws, hb_ws, hs_ws);
  k5_out     <<<BS / 64,   256, 0, stream>>>(x, WC, bC, hs_ws, out);
}